// Round 11
// baseline (198.716 us; speedup 1.0000x reference)
//
#include <hip/hip_runtime.h>
#include <cmath>
#include <cstdint>

#define N_NODES 100000
#define SAMPLES 16
#define DIM 128
#define NBATCH 8192

#define FSTR 264    // f16 LDS row stride (256 + 8 pad)
#define H2STR 132   // fp32 LDS row stride for layer2 h2 staging

typedef _Float16 half8 __attribute__((ext_vector_type(8)));
typedef float floatx4 __attribute__((ext_vector_type(4)));

__device__ __forceinline__ half8 h8max(half8 a, half8 b) {
    half8 r;
#pragma unroll
    for (int i = 0; i < 8; ++i) r[i] = (a[i] > b[i]) ? a[i] : b[i];
    return r;
}

// Fused setup: cvt_x [0,6250) | swizzle_w [6250,6282) | mark_flags [6282,6314)
// flags semantics: "flagged" == (flags[i] == 1); d_ws arrives 0xAA-poisoned so
// no zero pass is needed (garbage != 1; accidental 1 only adds work, never drops).
__global__ __launch_bounds__(256) void setup_kernel(
    const float* __restrict__ x,
    const float* __restrict__ W1,
    const float* __restrict__ W2,
    const int* __restrict__ batch,
    const int* __restrict__ nidx,
    int* __restrict__ flags,
    _Float16* __restrict__ xh,
    _Float16* __restrict__ W1sw,
    _Float16* __restrict__ W2sw) {
    const int bid = blockIdx.x;
    if (bid < 6250) {
        const size_t base = ((size_t)bid * 256 + threadIdx.x) * 8;
        const float4* xp = (const float4*)(x + base);
        const float4 a = xp[0], b = xp[1];
        half8 v;
        v[0] = (_Float16)a.x; v[1] = (_Float16)a.y;
        v[2] = (_Float16)a.z; v[3] = (_Float16)a.w;
        v[4] = (_Float16)b.x; v[5] = (_Float16)b.y;
        v[6] = (_Float16)b.z; v[7] = (_Float16)b.w;
        *(half8*)(xh + base) = v;
    } else if (bid < 6282) {
        // W[256][128] -> f16 B-fragment order for mfma_f32_16x16x32_f16:
        // frag (kb,nb,lane): B[k=kb*32+(lane>>4)*8+j][n=nb*16+(lane&15)]
        const int tid = (bid - 6250) * 256 + threadIdx.x;  // [0, 8192)
        const int which = tid >> 12;
        const int r = tid & 4095;
        const int kb = r >> 9, nb = (r >> 6) & 7, lane = r & 63;
        const int q = lane >> 4, c = lane & 15;
        const float* W = which ? W2 : W1;
        _Float16* O = which ? W2sw : W1sw;
        const int k0 = kb * 32 + q * 8;
        const int n = nb * 16 + c;
        half8 v;
#pragma unroll
        for (int j = 0; j < 8; ++j) v[j] = (_Float16)W[(size_t)(k0 + j) * DIM + n];
        *(half8*)(O + (size_t)r * 8) = v;
    } else {
        const int j = (bid - 6282) * 256 + threadIdx.x;
        if (j < NBATCH) {
            const int b = batch[j];
            flags[b] = 1;
            const int* row = nidx + (size_t)b * SAMPLES;
#pragma unroll
            for (int s = 0; s < SAMPLES; ++s) flags[row[s]] = 1;
        }
    }
}

// Software-pipelined fused layer1.
// Block = 512 threads (8 waves), 64 nodes as two 32-node tiles.
// Wave w owns N-tile nb=w: its 8 B-fragments are preloaded into registers
// BEFORE any gather load issues, so the MFMA phase consumes only LDS+regs
// (no vmcnt waits) and tile-1's gather loads stay in flight across it.
__global__ __launch_bounds__(512, 2) void layer1_kernel(
    const _Float16* __restrict__ xh,
    const int* __restrict__ nidx,
    const _Float16* __restrict__ W1sw,
    const float* __restrict__ b1,
    const int* __restrict__ flags,
    _Float16* __restrict__ h1h) {
    const int t = threadIdx.x;
    const int g = t >> 4;        // gather slot 0..31
    const int cl = t & 15;       // 16B chunk 0..15
    const int wave = t >> 6;     // 0..7 == owned nb
    const int lane = t & 63;
    const int q = lane >> 4, c = lane & 15;
    const int base = blockIdx.x * 64;

    __shared__ __align__(16) _Float16 feats[2][32 * FSTR];

    // ---- B preload (wave-persistent; issued before all gather VMEM) ----
    half8 bfr[8];
#pragma unroll
    for (int kb = 0; kb < 8; ++kb)
        bfr[kb] = *(const half8*)(W1sw + (size_t)((kb * 8 + wave) * 64 + lane) * 8);

    // ---- tile-0 gather (issue + reduce + store) ----
    {
        const int i = base + g;
        const bool fi = (i < N_NODES) && (flags[i] == 1);
        half8 self, mx;
        if (fi) {
            const char* xb = (const char*)xh;
            const int cb = cl * 16;
            self = *(const half8*)(xb + (size_t)i * 256 + cb);
            const int4* ip = (const int4*)(nidx + (size_t)i * SAMPLES);
            const int4 a0 = ip[0], a1 = ip[1], a2 = ip[2], a3 = ip[3];
            int off[16];
            off[0]  = a0.x * 256 + cb; off[1]  = a0.y * 256 + cb;
            off[2]  = a0.z * 256 + cb; off[3]  = a0.w * 256 + cb;
            off[4]  = a1.x * 256 + cb; off[5]  = a1.y * 256 + cb;
            off[6]  = a1.z * 256 + cb; off[7]  = a1.w * 256 + cb;
            off[8]  = a2.x * 256 + cb; off[9]  = a2.y * 256 + cb;
            off[10] = a2.z * 256 + cb; off[11] = a2.w * 256 + cb;
            off[12] = a3.x * 256 + cb; off[13] = a3.y * 256 + cb;
            off[14] = a3.z * 256 + cb; off[15] = a3.w * 256 + cb;
            half8 v[16];
#pragma unroll
            for (int s = 0; s < 16; ++s) v[s] = *(const half8*)(xb + off[s]);
#pragma unroll
            for (int s = 0; s < 8; ++s) v[s] = h8max(v[s], v[s + 8]);
#pragma unroll
            for (int s = 0; s < 4; ++s) v[s] = h8max(v[s], v[s + 4]);
            mx = h8max(h8max(v[0], v[1]), h8max(v[2], v[3]));
        } else {
#pragma unroll
            for (int e = 0; e < 8; ++e) { self[e] = (_Float16)0.f; mx[e] = (_Float16)0.f; }
        }
        *(half8*)(feats[0] + g * FSTR + cl * 8) = self;
        *(half8*)(feats[0] + g * FSTR + DIM + cl * 8) = mx;
    }
    __syncthreads();

    // ---- tile-1 gather: ISSUE loads only (stay in flight across MFMA) ----
    const int n1 = base + 32 + g;
    const bool f1 = (n1 < N_NODES) && (flags[n1] == 1);
    half8 v1[16], self1;
    const int cb = cl * 16;
    if (f1) {
        const char* xb = (const char*)xh;
        const int4* ip = (const int4*)(nidx + (size_t)n1 * SAMPLES);
        const int4 a0 = ip[0], a1 = ip[1], a2 = ip[2], a3 = ip[3];
        self1 = *(const half8*)(xb + (size_t)n1 * 256 + cb);
        v1[0]  = *(const half8*)(xb + (size_t)(a0.x * 256 + cb));
        v1[1]  = *(const half8*)(xb + (size_t)(a0.y * 256 + cb));
        v1[2]  = *(const half8*)(xb + (size_t)(a0.z * 256 + cb));
        v1[3]  = *(const half8*)(xb + (size_t)(a0.w * 256 + cb));
        v1[4]  = *(const half8*)(xb + (size_t)(a1.x * 256 + cb));
        v1[5]  = *(const half8*)(xb + (size_t)(a1.y * 256 + cb));
        v1[6]  = *(const half8*)(xb + (size_t)(a1.z * 256 + cb));
        v1[7]  = *(const half8*)(xb + (size_t)(a1.w * 256 + cb));
        v1[8]  = *(const half8*)(xb + (size_t)(a2.x * 256 + cb));
        v1[9]  = *(const half8*)(xb + (size_t)(a2.y * 256 + cb));
        v1[10] = *(const half8*)(xb + (size_t)(a2.z * 256 + cb));
        v1[11] = *(const half8*)(xb + (size_t)(a2.w * 256 + cb));
        v1[12] = *(const half8*)(xb + (size_t)(a3.x * 256 + cb));
        v1[13] = *(const half8*)(xb + (size_t)(a3.y * 256 + cb));
        v1[14] = *(const half8*)(xb + (size_t)(a3.z * 256 + cb));
        v1[15] = *(const half8*)(xb + (size_t)(a3.w * 256 + cb));
    }
    __builtin_amdgcn_sched_barrier(0);

    // ---- tile-0 MFMA (VMEM-free: A from LDS, B from registers) ----
    floatx4 acc0[2];
    acc0[0] = (floatx4){0.f, 0.f, 0.f, 0.f};
    acc0[1] = (floatx4){0.f, 0.f, 0.f, 0.f};
#pragma unroll
    for (int ms = 0; ms < 2; ++ms) {
        const _Float16* fp = feats[0] + (ms * 16 + c) * FSTR;
#pragma unroll
        for (int kb = 0; kb < 8; ++kb) {
            const half8 a = *(const half8*)(fp + kb * 32 + q * 8);
            acc0[ms] = __builtin_amdgcn_mfma_f32_16x16x32_f16(a, bfr[kb], acc0[ms], 0, 0, 0);
        }
    }
    __builtin_amdgcn_sched_barrier(0);

    // ---- tile-1 reduce (drains vmcnt AFTER the MFMA phase) + store ----
    if (f1) {
#pragma unroll
        for (int s = 0; s < 8; ++s) v1[s] = h8max(v1[s], v1[s + 8]);
#pragma unroll
        for (int s = 0; s < 4; ++s) v1[s] = h8max(v1[s], v1[s + 4]);
        const half8 mx = h8max(h8max(v1[0], v1[1]), h8max(v1[2], v1[3]));
        *(half8*)(feats[1] + g * FSTR + cl * 8) = self1;
        *(half8*)(feats[1] + g * FSTR + DIM + cl * 8) = mx;
    } else {
        half8 z;
#pragma unroll
        for (int e = 0; e < 8; ++e) z[e] = (_Float16)0.f;
        *(half8*)(feats[1] + g * FSTR + cl * 8) = z;
        *(half8*)(feats[1] + g * FSTR + DIM + cl * 8) = z;
    }

    // ---- tile-0 epilogue (after reduce so its stores don't sit in the drain) ----
    const int n = wave * 16 + c;
    const float bias = b1[n];
#pragma unroll
    for (int ms = 0; ms < 2; ++ms) {
#pragma unroll
        for (int r = 0; r < 4; ++r) {
            const int node = base + ms * 16 + q * 4 + r;
            if (node < N_NODES && flags[node] == 1) {
                const float val = fmaxf(acc0[ms][r] + bias, 0.f);
                h1h[(size_t)node * DIM + n] = (_Float16)val;
            }
        }
    }
    __syncthreads();

    // ---- tile-1 MFMA + epilogue ----
    floatx4 acc1[2];
    acc1[0] = (floatx4){0.f, 0.f, 0.f, 0.f};
    acc1[1] = (floatx4){0.f, 0.f, 0.f, 0.f};
#pragma unroll
    for (int ms = 0; ms < 2; ++ms) {
        const _Float16* fp = feats[1] + (ms * 16 + c) * FSTR;
#pragma unroll
        for (int kb = 0; kb < 8; ++kb) {
            const half8 a = *(const half8*)(fp + kb * 32 + q * 8);
            acc1[ms] = __builtin_amdgcn_mfma_f32_16x16x32_f16(a, bfr[kb], acc1[ms], 0, 0, 0);
        }
    }
#pragma unroll
    for (int ms = 0; ms < 2; ++ms) {
#pragma unroll
        for (int r = 0; r < 4; ++r) {
            const int node = base + 32 + ms * 16 + q * 4 + r;
            if (node < N_NODES && flags[node] == 1) {
                const float val = fmaxf(acc1[ms][r] + bias, 0.f);
                h1h[(size_t)node * DIM + n] = (_Float16)val;
            }
        }
    }
}

// Cooperative layer2: 256 threads / 16 batch rows; gather + MFMA + fused proj_out.
__global__ __launch_bounds__(256) void layer2_kernel(
    const _Float16* __restrict__ h1h,
    const int* __restrict__ nidx,
    const int* __restrict__ batch,
    const _Float16* __restrict__ W2sw,
    const float* __restrict__ b2,
    const float* __restrict__ Wout,
    const float* __restrict__ bout,
    float* __restrict__ out) {
    const int t = threadIdx.x;
    const int wave = t >> 6;
    const int lane = t & 63;
    const int q = lane >> 4, c = lane & 15;
    const int w0 = blockIdx.x * 16;

    __shared__ __align__(16) _Float16 feats[16 * FSTR];
    __shared__ __align__(16) float h2s[16 * H2STR];

    // ---- gather ----
    {
        const int m = t >> 4;
        const int cl = t & 15;
        const int node = batch[w0 + m];
        const char* hb = (const char*)h1h;
        const int cb = cl * 16;
        const half8 self = *(const half8*)(hb + (size_t)node * 256 + cb);
        const int4* ip = (const int4*)(nidx + (size_t)node * SAMPLES);
        const int4 a0 = ip[0], a1 = ip[1], a2 = ip[2], a3 = ip[3];
        int off[16];
        off[0]  = a0.x * 256 + cb; off[1]  = a0.y * 256 + cb;
        off[2]  = a0.z * 256 + cb; off[3]  = a0.w * 256 + cb;
        off[4]  = a1.x * 256 + cb; off[5]  = a1.y * 256 + cb;
        off[6]  = a1.z * 256 + cb; off[7]  = a1.w * 256 + cb;
        off[8]  = a2.x * 256 + cb; off[9]  = a2.y * 256 + cb;
        off[10] = a2.z * 256 + cb; off[11] = a2.w * 256 + cb;
        off[12] = a3.x * 256 + cb; off[13] = a3.y * 256 + cb;
        off[14] = a3.z * 256 + cb; off[15] = a3.w * 256 + cb;
        half8 v[16];
#pragma unroll
        for (int s = 0; s < 16; ++s) v[s] = *(const half8*)(hb + off[s]);
#pragma unroll
        for (int s = 0; s < 8; ++s) v[s] = h8max(v[s], v[s + 8]);
#pragma unroll
        for (int s = 0; s < 4; ++s) v[s] = h8max(v[s], v[s + 4]);
        const half8 mx = h8max(h8max(v[0], v[1]), h8max(v[2], v[3]));
        *(half8*)(feats + m * FSTR + cl * 8) = self;
        *(half8*)(feats + m * FSTR + DIM + cl * 8) = mx;
    }
    __syncthreads();

    // ---- MFMA: wave computes nb = 2*wave, 2*wave+1 over K=256 ----
    const int nb0 = wave * 2;
    floatx4 acc[2];
    acc[0] = (floatx4){0.f, 0.f, 0.f, 0.f};
    acc[1] = (floatx4){0.f, 0.f, 0.f, 0.f};
#pragma unroll
    for (int kb = 0; kb < 8; ++kb) {
        const half8 a = *(const half8*)(feats + c * FSTR + kb * 32 + q * 8);
#pragma unroll
        for (int j = 0; j < 2; ++j) {
            const half8 b = *(const half8*)(W2sw + (size_t)((kb * 8 + nb0 + j) * 64 + lane) * 8);
            acc[j] = __builtin_amdgcn_mfma_f32_16x16x32_f16(a, b, acc[j], 0, 0, 0);
        }
    }
#pragma unroll
    for (int j = 0; j < 2; ++j) {
        const int n = (nb0 + j) * 16 + c;
        const float bias = b2[n];
#pragma unroll
        for (int r = 0; r < 4; ++r)
            h2s[(q * 4 + r) * H2STR + n] = acc[j][r] + bias;
    }
    __syncthreads();

    // ---- proj_out: wave handles rows wave*4..+3; lane = output dim ----
    float accs[4];
    const float bo = bout[lane];
#pragma unroll
    for (int r = 0; r < 4; ++r) accs[r] = bo;
    for (int k4 = 0; k4 < DIM; k4 += 4) {
        float wv[4];
#pragma unroll
        for (int j = 0; j < 4; ++j) wv[j] = Wout[(size_t)(k4 + j) * 64 + lane];
#pragma unroll
        for (int r = 0; r < 4; ++r) {
            const float4 f = *(const float4*)&h2s[(wave * 4 + r) * H2STR + k4];
            accs[r] += f.x * wv[0] + f.y * wv[1] + f.z * wv[2] + f.w * wv[3];
        }
    }
#pragma unroll
    for (int r = 0; r < 4; ++r)
        out[(size_t)(w0 + wave * 4 + r) * 64 + lane] = accs[r];
}

extern "C" void kernel_launch(void* const* d_in, const int* in_sizes, int n_in,
                              void* d_out, int out_size, void* d_ws, size_t ws_size,
                              hipStream_t stream) {
    const float* x    = (const float*)d_in[0];
    const int* nidx   = (const int*)d_in[1];
    const int* batch  = (const int*)d_in[2];
    const float* W1   = (const float*)d_in[3];
    const float* b1   = (const float*)d_in[4];
    const float* W2   = (const float*)d_in[5];
    const float* b2   = (const float*)d_in[6];
    const float* Wout = (const float*)d_in[7];
    const float* bout = (const float*)d_in[8];
    float* out        = (float*)d_out;

    // ws layout (bytes):
    //   [0, 400000)           flags (poison-based: flagged == 1)
    //   [409600, 475136)      W1sw f16
    //   [475136, 540672)      W2sw f16
    //   [540672, 26140672)    xh   f16
    //   [26140672, 51740672)  h1h  f16
    int* flags      = (int*)d_ws;
    _Float16* W1sw  = (_Float16*)((char*)d_ws + 409600);
    _Float16* W2sw  = (_Float16*)((char*)d_ws + 475136);
    _Float16* xh    = (_Float16*)((char*)d_ws + 540672);
    _Float16* h1h   = (_Float16*)((char*)d_ws + 26140672);

    setup_kernel<<<6314, 256, 0, stream>>>(x, W1, W2, batch, nidx, flags, xh, W1sw, W2sw);
    layer1_kernel<<<(N_NODES + 63) / 64, 512, 0, stream>>>(xh, nidx, W1sw, b1, flags, h1h);
    layer2_kernel<<<NBATCH / 16, 256, 0, stream>>>(h1h, nidx, batch, W2sw, b2, Wout, bout, out);
}

// Round 12
// 173.299 us; speedup vs baseline: 1.1467x; 1.1467x over previous
//
#include <hip/hip_runtime.h>
#include <cmath>
#include <cstdint>

#define N_NODES 100000
#define SAMPLES 16
#define DIM 128
#define NBATCH 8192

#define FSTR 264    // f16 LDS row stride (256 + 8 pad)
#define H2STR 132   // fp32 LDS row stride for layer2 h2 staging

typedef _Float16 half8 __attribute__((ext_vector_type(8)));
typedef float floatx4 __attribute__((ext_vector_type(4)));

__device__ __forceinline__ half8 h8max(half8 a, half8 b) {
    half8 r;
#pragma unroll
    for (int i = 0; i < 8; ++i) r[i] = (a[i] > b[i]) ? a[i] : b[i];
    return r;
}

// Fused setup: cvt_x [0,6250) | swizzle_w [6250,6282) | mark_flags [6282,6314)
// flags semantics: "flagged" == (flags[i] == 1); d_ws arrives 0xAA-poisoned so
// no zero pass is needed (garbage != 1; accidental 1 only adds work, never drops).
__global__ __launch_bounds__(256) void setup_kernel(
    const float* __restrict__ x,
    const float* __restrict__ W1,
    const float* __restrict__ W2,
    const int* __restrict__ batch,
    const int* __restrict__ nidx,
    int* __restrict__ flags,
    _Float16* __restrict__ xh,
    _Float16* __restrict__ W1sw,
    _Float16* __restrict__ W2sw) {
    const int bid = blockIdx.x;
    if (bid < 6250) {
        const size_t base = ((size_t)bid * 256 + threadIdx.x) * 8;
        const float4* xp = (const float4*)(x + base);
        const float4 a = xp[0], b = xp[1];
        half8 v;
        v[0] = (_Float16)a.x; v[1] = (_Float16)a.y;
        v[2] = (_Float16)a.z; v[3] = (_Float16)a.w;
        v[4] = (_Float16)b.x; v[5] = (_Float16)b.y;
        v[6] = (_Float16)b.z; v[7] = (_Float16)b.w;
        *(half8*)(xh + base) = v;
    } else if (bid < 6282) {
        // W[256][128] -> f16 B-fragment order for mfma_f32_16x16x32_f16:
        // frag (kb,nb,lane): B[k=kb*32+(lane>>4)*8+j][n=nb*16+(lane&15)]
        const int tid = (bid - 6250) * 256 + threadIdx.x;  // [0, 8192)
        const int which = tid >> 12;
        const int r = tid & 4095;
        const int kb = r >> 9, nb = (r >> 6) & 7, lane = r & 63;
        const int q = lane >> 4, c = lane & 15;
        const float* W = which ? W2 : W1;
        _Float16* O = which ? W2sw : W1sw;
        const int k0 = kb * 32 + q * 8;
        const int n = nb * 16 + c;
        half8 v;
#pragma unroll
        for (int j = 0; j < 8; ++j) v[j] = (_Float16)W[(size_t)(k0 + j) * DIM + n];
        *(half8*)(O + (size_t)r * 8) = v;
    } else {
        const int j = (bid - 6282) * 256 + threadIdx.x;
        if (j < NBATCH) {
            const int b = batch[j];
            flags[b] = 1;
            const int* row = nidx + (size_t)b * SAMPLES;
#pragma unroll
            for (int s = 0; s < SAMPLES; ++s) flags[row[s]] = 1;
        }
    }
}

// layer1 (round-8 structure): block = 256 threads = 16 nodes. 16-lane group g
// gathers node blockIdx*16+g (each lane one 16B chunk -> full-256B coalesced
// row reads, all 16 groups' 17-load gathers concurrent). 4 waves split MFMA
// by N. Epilogue h1h stores are NON-TEMPORAL: they are consumed only by the
// later layer2 kernel, so don't let 19 MB of stores evict xh from L2.
__global__ __launch_bounds__(256) void layer1_kernel(
    const _Float16* __restrict__ xh,
    const int* __restrict__ nidx,
    const _Float16* __restrict__ W1sw,
    const float* __restrict__ b1,
    const int* __restrict__ flags,
    _Float16* __restrict__ h1h) {
    const int t = threadIdx.x;
    const int g = t >> 4;        // node slot 0..15
    const int cl = t & 15;       // 16B chunk 0..15
    const int i0 = blockIdx.x * 16;
    const int i = i0 + g;        // 6250*16 == 100000 exactly

    __shared__ __align__(16) _Float16 feats[16 * FSTR];

    const bool fi = (flags[i] == 1);
    if (fi) {
        const char* xb = (const char*)xh;
        const int cb = cl * 16;
        const half8 self = *(const half8*)(xb + (size_t)i * 256 + cb);
        const int4* ip = (const int4*)(nidx + (size_t)i * SAMPLES);
        const int4 a0 = ip[0], a1 = ip[1], a2 = ip[2], a3 = ip[3];
        int off[16];
        off[0]  = a0.x * 256 + cb; off[1]  = a0.y * 256 + cb;
        off[2]  = a0.z * 256 + cb; off[3]  = a0.w * 256 + cb;
        off[4]  = a1.x * 256 + cb; off[5]  = a1.y * 256 + cb;
        off[6]  = a1.z * 256 + cb; off[7]  = a1.w * 256 + cb;
        off[8]  = a2.x * 256 + cb; off[9]  = a2.y * 256 + cb;
        off[10] = a2.z * 256 + cb; off[11] = a2.w * 256 + cb;
        off[12] = a3.x * 256 + cb; off[13] = a3.y * 256 + cb;
        off[14] = a3.z * 256 + cb; off[15] = a3.w * 256 + cb;
        half8 v[16];
#pragma unroll
        for (int s = 0; s < 16; ++s) v[s] = *(const half8*)(xb + off[s]);
#pragma unroll
        for (int s = 0; s < 8; ++s) v[s] = h8max(v[s], v[s + 8]);
#pragma unroll
        for (int s = 0; s < 4; ++s) v[s] = h8max(v[s], v[s + 4]);
        const half8 mx = h8max(h8max(v[0], v[1]), h8max(v[2], v[3]));
        *(half8*)(feats + g * FSTR + cl * 8) = self;
        *(half8*)(feats + g * FSTR + DIM + cl * 8) = mx;
    } else {
        half8 z;
#pragma unroll
        for (int e = 0; e < 8; ++e) z[e] = (_Float16)0.f;
        *(half8*)(feats + g * FSTR + cl * 8) = z;
        *(half8*)(feats + g * FSTR + DIM + cl * 8) = z;
    }
    __syncthreads();

    // MFMA: wave w computes nb = 2w, 2w+1 over K=256.
    // A[m=c][k=kb*32+q*8+j] from LDS; B from pre-swizzled W1; D[m=q*4+r][n=nb*16+c]
    const int wave = t >> 6;
    const int lane = t & 63;
    const int q = lane >> 4, c = lane & 15;
    const int nb0 = wave * 2;
    floatx4 acc[2];
    acc[0] = (floatx4){0.f, 0.f, 0.f, 0.f};
    acc[1] = (floatx4){0.f, 0.f, 0.f, 0.f};
#pragma unroll
    for (int kb = 0; kb < 8; ++kb) {
        const half8 a = *(const half8*)(feats + c * FSTR + kb * 32 + q * 8);
#pragma unroll
        for (int j = 0; j < 2; ++j) {
            const half8 b = *(const half8*)(W1sw + (size_t)((kb * 8 + nb0 + j) * 64 + lane) * 8);
            acc[j] = __builtin_amdgcn_mfma_f32_16x16x32_f16(a, b, acc[j], 0, 0, 0);
        }
    }

    // epilogue: bias + relu + non-temporal f16 store, gated per stored row
#pragma unroll
    for (int r = 0; r < 4; ++r) {
        const int node = i0 + q * 4 + r;
        if (flags[node] != 1) continue;
#pragma unroll
        for (int j = 0; j < 2; ++j) {
            const int n = (nb0 + j) * 16 + c;
            const float v = fmaxf(acc[j][r] + b1[n], 0.f);
            const _Float16 hv = (_Float16)v;
            __builtin_nontemporal_store(hv, h1h + (size_t)node * DIM + n);
        }
    }
}

// Cooperative layer2: 256 threads / 16 batch rows; gather + MFMA + fused proj_out.
__global__ __launch_bounds__(256) void layer2_kernel(
    const _Float16* __restrict__ h1h,
    const int* __restrict__ nidx,
    const int* __restrict__ batch,
    const _Float16* __restrict__ W2sw,
    const float* __restrict__ b2,
    const float* __restrict__ Wout,
    const float* __restrict__ bout,
    float* __restrict__ out) {
    const int t = threadIdx.x;
    const int wave = t >> 6;
    const int lane = t & 63;
    const int q = lane >> 4, c = lane & 15;
    const int w0 = blockIdx.x * 16;

    __shared__ __align__(16) _Float16 feats[16 * FSTR];
    __shared__ __align__(16) float h2s[16 * H2STR];

    // ---- gather ----
    {
        const int m = t >> 4;
        const int cl = t & 15;
        const int node = batch[w0 + m];
        const char* hb = (const char*)h1h;
        const int cb = cl * 16;
        const half8 self = *(const half8*)(hb + (size_t)node * 256 + cb);
        const int4* ip = (const int4*)(nidx + (size_t)node * SAMPLES);
        const int4 a0 = ip[0], a1 = ip[1], a2 = ip[2], a3 = ip[3];
        int off[16];
        off[0]  = a0.x * 256 + cb; off[1]  = a0.y * 256 + cb;
        off[2]  = a0.z * 256 + cb; off[3]  = a0.w * 256 + cb;
        off[4]  = a1.x * 256 + cb; off[5]  = a1.y * 256 + cb;
        off[6]  = a1.z * 256 + cb; off[7]  = a1.w * 256 + cb;
        off[8]  = a2.x * 256 + cb; off[9]  = a2.y * 256 + cb;
        off[10] = a2.z * 256 + cb; off[11] = a2.w * 256 + cb;
        off[12] = a3.x * 256 + cb; off[13] = a3.y * 256 + cb;
        off[14] = a3.z * 256 + cb; off[15] = a3.w * 256 + cb;
        half8 v[16];
#pragma unroll
        for (int s = 0; s < 16; ++s) v[s] = *(const half8*)(hb + off[s]);
#pragma unroll
        for (int s = 0; s < 8; ++s) v[s] = h8max(v[s], v[s + 8]);
#pragma unroll
        for (int s = 0; s < 4; ++s) v[s] = h8max(v[s], v[s + 4]);
        const half8 mx = h8max(h8max(v[0], v[1]), h8max(v[2], v[3]));
        *(half8*)(feats + m * FSTR + cl * 8) = self;
        *(half8*)(feats + m * FSTR + DIM + cl * 8) = mx;
    }
    __syncthreads();

    // ---- MFMA: wave computes nb = 2*wave, 2*wave+1 over K=256 ----
    const int nb0 = wave * 2;
    floatx4 acc[2];
    acc[0] = (floatx4){0.f, 0.f, 0.f, 0.f};
    acc[1] = (floatx4){0.f, 0.f, 0.f, 0.f};
#pragma unroll
    for (int kb = 0; kb < 8; ++kb) {
        const half8 a = *(const half8*)(feats + c * FSTR + kb * 32 + q * 8);
#pragma unroll
        for (int j = 0; j < 2; ++j) {
            const half8 b = *(const half8*)(W2sw + (size_t)((kb * 8 + nb0 + j) * 64 + lane) * 8);
            acc[j] = __builtin_amdgcn_mfma_f32_16x16x32_f16(a, b, acc[j], 0, 0, 0);
        }
    }
#pragma unroll
    for (int j = 0; j < 2; ++j) {
        const int n = (nb0 + j) * 16 + c;
        const float bias = b2[n];
#pragma unroll
        for (int r = 0; r < 4; ++r)
            h2s[(q * 4 + r) * H2STR + n] = acc[j][r] + bias;
    }
    __syncthreads();

    // ---- proj_out: wave handles rows wave*4..+3; lane = output dim ----
    float accs[4];
    const float bo = bout[lane];
#pragma unroll
    for (int r = 0; r < 4; ++r) accs[r] = bo;
    for (int k4 = 0; k4 < DIM; k4 += 4) {
        float wv[4];
#pragma unroll
        for (int j = 0; j < 4; ++j) wv[j] = Wout[(size_t)(k4 + j) * 64 + lane];
#pragma unroll
        for (int r = 0; r < 4; ++r) {
            const float4 f = *(const float4*)&h2s[(wave * 4 + r) * H2STR + k4];
            accs[r] += f.x * wv[0] + f.y * wv[1] + f.z * wv[2] + f.w * wv[3];
        }
    }
#pragma unroll
    for (int r = 0; r < 4; ++r)
        __builtin_nontemporal_store(accs[r], out + (size_t)(w0 + wave * 4 + r) * 64 + lane);
}

extern "C" void kernel_launch(void* const* d_in, const int* in_sizes, int n_in,
                              void* d_out, int out_size, void* d_ws, size_t ws_size,
                              hipStream_t stream) {
    const float* x    = (const float*)d_in[0];
    const int* nidx   = (const int*)d_in[1];
    const int* batch  = (const int*)d_in[2];
    const float* W1   = (const float*)d_in[3];
    const float* b1   = (const float*)d_in[4];
    const float* W2   = (const float*)d_in[5];
    const float* b2   = (const float*)d_in[6];
    const float* Wout = (const float*)d_in[7];
    const float* bout = (const float*)d_in[8];
    float* out        = (float*)d_out;

    // ws layout (bytes):
    //   [0, 400000)           flags (poison-based: flagged == 1)
    //   [409600, 475136)      W1sw f16
    //   [475136, 540672)      W2sw f16
    //   [540672, 26140672)    xh   f16
    //   [26140672, 51740672)  h1h  f16
    int* flags      = (int*)d_ws;
    _Float16* W1sw  = (_Float16*)((char*)d_ws + 409600);
    _Float16* W2sw  = (_Float16*)((char*)d_ws + 475136);
    _Float16* xh    = (_Float16*)((char*)d_ws + 540672);
    _Float16* h1h   = (_Float16*)((char*)d_ws + 26140672);

    setup_kernel<<<6314, 256, 0, stream>>>(x, W1, W2, batch, nidx, flags, xh, W1sw, W2sw);
    layer1_kernel<<<N_NODES / 16, 256, 0, stream>>>(xh, nidx, W1sw, b1, flags, h1h);
    layer2_kernel<<<NBATCH / 16, 256, 0, stream>>>(h1h, nidx, batch, W2sw, b2, Wout, bout, out);
}